// Round 9
// baseline (202.671 us; speedup 1.0000x reference)
//
#include <hip/hip_runtime.h>
#include <math.h>

#define BN_EPS 1e-5f

using short8  = __attribute__((ext_vector_type(8))) short;
using f32x16  = __attribute__((ext_vector_type(16))) float;

// ---------------------------------------------------------------------------
// x (16,640,32,32) fp32. Pixels P=16384, p = b*1024 + h*32 + w.
// feat K-order (permuted): kg'<64 -> identity ch kg'; kg'>=64: t=kg'-64,
//   ksp=t>>6 (spatial 0..24), c=t&63; orig w_emb col = 64 + c*25 + ksp.
// Weight tiles (A-frag order), per kc (K=32 chunk): see k_prepAll.
// xpk: bf16(relu(BN(x))) pre-packed for phase 0a:
//   byte ((b*20+kc)*1024 + p)*64 + o*16, o = octet: ch = kc*32 + o*8 + j.
//
// k_mega v3 (identity+feat+emb+out), one block per 64-px tile, 640 thr =
// 10 waves, wave w owns oc [64w,64w+64).
//  - phase 0a: pure load+MFMA (B-frags read from xpk; BN/relu/pack hoisted
//    to prepAll). 2 B-loads + 4 A-loads + 4 MFMA per kc, 1-ahead prefetch.
//  - phase 1: 8-kc chunks, rolling prefetch of next-kc A (L2) and B (LDS).
//  - phase 3: rolling prefetch of A and Ep fragments.
//  - LDS aliased: {slab|ctrs+invD+stg dbuf} reused as Ep. Peak 106112 B.
// ---------------------------------------------------------------------------

__device__ __forceinline__ float bflo(unsigned u) { return __uint_as_float(u << 16); }
__device__ __forceinline__ float bfhi(unsigned u) { return __uint_as_float(u & 0xffff0000u); }

__device__ __forceinline__ unsigned bf16_rne(float f) {
    unsigned u = __float_as_uint(f);
    return (u + 0x7fffu + ((u >> 16) & 1u)) >> 16;
}
__device__ __forceinline__ unsigned pack_bf16(float lo, float hi) {
    return bf16_rne(lo) | (bf16_rne(hi) << 16);
}
__device__ __forceinline__ unsigned pk_hu(float lo, float hi) {
    unsigned a = __float_as_uint(lo) + 0x8000u;
    unsigned b = __float_as_uint(hi) + 0x8000u;
    return __builtin_amdgcn_perm(b, a, 0x07060302u);
}
__device__ __forceinline__ unsigned pmul_fast(unsigned a, unsigned b) {
    return pk_hu(bflo(a) * bflo(b), bfhi(a) * bfhi(b));
}

// ===========================================================================
// k_prepAll: blocks [0,640) build wEt; blocks [640,872) scalars + wIt + wOt;
//            blocks [872,1192) build xpk = bf16(relu(BN(x))) in 0a B-order.
// ===========================================================================
__global__ __launch_bounds__(256)
void k_prepAll(const float* __restrict__ x,
               const float* __restrict__ g1, const float* __restrict__ b1,
               const float* __restrict__ m1, const float* __restrict__ v1,
               const float* __restrict__ w_in,
               const float* __restrict__ gi, const float* __restrict__ bi,
               const float* __restrict__ mi, const float* __restrict__ vi,
               const float* __restrict__ w_emb,
               const float* __restrict__ ge, const float* __restrict__ be,
               const float* __restrict__ me, const float* __restrict__ ve,
               const float* __restrict__ w_out,
               const float* __restrict__ go, const float* __restrict__ bo,
               const float* __restrict__ mo, const float* __restrict__ vo,
               float* __restrict__ biasI, float* __restrict__ biasE, float* __restrict__ biasO,
               unsigned* __restrict__ wIt, unsigned* __restrict__ wEt, unsigned* __restrict__ wOt,
               unsigned* __restrict__ xpk)
{
    __shared__ float row[1664];
    const int tid = threadIdx.x;

    if (blockIdx.x >= 872) {             // ---- xpk generation ----
        const int id2 = blockIdx.x - 872;
        const int b = id2 / 20, kc = id2 - b * 20;
#pragma unroll 4
        for (int it = 0; it < 16; it++) {
            const int co8 = it >> 2;
            const int p = (it & 3) * 256 + tid;
            const int ch0 = kc * 32 + co8 * 8;
            unsigned d[4];
#pragma unroll
            for (int q = 0; q < 4; q++) {
                float v[2];
#pragma unroll
                for (int h = 0; h < 2; h++) {
                    int ch = ch0 + 2 * q + h;
                    float sc = g1[ch] * rsqrtf(v1[ch] + BN_EPS);
                    float bc = b1[ch] - m1[ch] * sc;
                    v[h] = fmaxf(fmaf(x[((size_t)b * 640 + ch) * 1024 + p], sc, bc), 0.f);
                }
                d[q] = pack_bf16(v[0], v[1]);
            }
            *(uint4*)((char*)xpk + (((size_t)(b * 20 + kc) * 1024 + p) * 64 + co8 * 16)) =
                make_uint4(d[0], d[1], d[2], d[3]);
        }
        return;
    }

    if (blockIdx.x < 640) {
        const int oc = blockIdx.x;
#pragma unroll
        for (int it = 0; it < 2; it++) {
            int u = it * 256 + tid;
            if (u < 416)
                ((float4*)row)[u] = ((const float4*)&w_emb[(size_t)oc * 1664])[u];
        }
        __syncthreads();
        if (tid < 208) {
            int kc = tid >> 2, kh = (tid >> 1) & 1, ksub = tid & 1;
            int k0 = kc * 32 + kh * 16 + ksub * 8;
            float sc = ge[oc] * rsqrtf(ve[oc] + BN_EPS);
            float v[8];
#pragma unroll
            for (int j = 0; j < 8; j++) {
                int kgp = k0 + j;
                int orig;
                if (kgp < 64) orig = kgp;
                else { int t = kgp - 64; orig = 64 + (t & 63) * 25 + (t >> 6); }
                v[j] = row[orig] * sc;
            }
            int mt = oc >> 7, mf = (oc >> 5) & 3;
            int idx = (mt * 52 + kc) * 512 + (mf * 2 + kh) * 64 + ksub * 32 + (oc & 31);
            ((uint4*)wEt)[idx] = make_uint4(pack_bf16(v[0], v[1]), pack_bf16(v[2], v[3]),
                                            pack_bf16(v[4], v[5]), pack_bf16(v[6], v[7]));
        }
        return;
    }

    int i = (blockIdx.x - 640) * 256 + tid;

    if (i < 64) {
        int c = i;
        float s = gi[c] * rsqrtf(vi[c] + BN_EPS);
        biasI[c] = bi[c] - mi[c] * s;
    } else if (i >= 704 && i < 1344) {
        int c = i - 704;
        float s = ge[c] * rsqrtf(ve[c] + BN_EPS);
        biasE[c] = be[c] - me[c] * s;
    } else if (i >= 1344 && i < 1984) {
        int c = i - 1344;
        float s = go[c] * rsqrtf(vo[c] + BN_EPS);
        biasO[c] = bo[c] - mo[c] * s;
    }

    if (i >= 2048 && i < 7168) {         // wIt
        int u = i - 2048;
        int kc = u >> 8, w = u & 255;
        int mf = w >> 7, kh = (w >> 6) & 1, sl = w & 63;
        int oc = mf * 32 + (sl & 31);
        int k0 = kc * 32 + kh * 16 + (sl >> 5) * 8;
        float sc = gi[oc] * rsqrtf(vi[oc] + BN_EPS);
        unsigned d[4];
#pragma unroll
        for (int q = 0; q < 4; q++)
            d[q] = pack_bf16(w_in[oc * 640 + k0 + 2 * q] * sc,
                             w_in[oc * 640 + k0 + 2 * q + 1] * sc);
        ((uint4*)wIt)[u] = make_uint4(d[0], d[1], d[2], d[3]);
    }

    if (i >= 8192 && i < 59392) {        // wOt
        int u = i - 8192;
        int ci = u >> 9, w = u & 511;
        int mt = ci / 20, kc = ci - mt * 20;
        int mf = w >> 7, kh = (w >> 6) & 1, sl = w & 63;
        int oc = mt * 128 + mf * 32 + (sl & 31);
        int k0 = kc * 32 + kh * 16 + (sl >> 5) * 8;
        float sc = go[oc] * rsqrtf(vo[oc] + BN_EPS);
        unsigned d[4];
#pragma unroll
        for (int q = 0; q < 4; q++)
            d[q] = pack_bf16(w_out[oc * 640 + k0 + 2 * q] * sc,
                             w_out[oc * 640 + k0 + 2 * q + 1] * sc);
        ((uint4*)wOt)[u] = make_uint4(d[0], d[1], d[2], d[3]);
    }
}

// ===========================================================================
// feat B-unit generator: unit (kcAbs, t) of the B-frag tile, from slab/ctrs.
// ===========================================================================
__device__ __forceinline__ uint4 gen_feat_unit(const short* slab, const short* ctrs,
                                               int kcAbs, int t)
{
    const int hf = t >> 7, sl = t & 63;
    const int bkh = (t >> 6) & 1;
    const int cl = bkh * 16 + (sl >> 5) * 8;
    if (kcAbs < 2) {
        int spxC = (hf + 2) * 36 + (sl & 31) + 2;
        return *(const uint4*)&slab[spxC * 72 + kcAbs * 32 + cl];
    } else {
        int pxl = hf * 32 + (sl & 31);
        int idx = kcAbs - 2;
        int ksp = idx >> 1;
        int cb = (idx & 1) * 32 + cl;
        int kho = ksp / 5, kwo = ksp - kho * 5;
        int spx = (hf + kho) * 36 + (sl & 31) + kwo;
        const unsigned* nb = (const unsigned*)&slab[spx * 72 + cb];
        const unsigned* ct = (const unsigned*)&ctrs[pxl * 72 + cb];
        return make_uint4(pmul_fast(nb[0], ct[0]), pmul_fast(nb[1], ct[1]),
                          pmul_fast(nb[2], ct[2]), pmul_fast(nb[3], ct[3]));
    }
}

// ===========================================================================
// k_mega v3: identity + feat + emb + out, one block per 64-px tile, 640 thr.
// LDS layout (106112 B total, aliased):
//   [0      , 31104) slab  (216 x 72 shorts)           -- phases 0a..1
//   [31104  , 40320) ctrs  (64 x 72 shorts)            -- phases 0c..1
//   [40320  , 40576) invD                               -- phase 0b..0c
//   [40576  , 106112) stg dbuf (2 x 32768 = 8 kc each)  -- phase 1
//   [0      ,  81920) Ep (20 kc x 256 uint4)            -- phases 2..3
// ===========================================================================
__global__ __launch_bounds__(640, 3)
void k_mega(const unsigned* __restrict__ xpk,
            const unsigned* __restrict__ wIt, const float* __restrict__ biasI,
            const unsigned* __restrict__ wEt, const float* __restrict__ biasE,
            const unsigned* __restrict__ wOt, const float* __restrict__ biasO,
            float* __restrict__ out)
{
    __shared__ __align__(16) char Lds[106112];
    short* slab  = (short*)Lds;
    short* ctrs  = (short*)(Lds + 31104);
    float* invDs = (float*)(Lds + 40320);
    char*  stg   = Lds + 40576;
    uint4* Ep    = (uint4*)Lds;

    const int tid = threadIdx.x;
    const int l = tid & 63;
    const int w = tid >> 6;              // wave 0..9, oc base = w*64
    const int mt = w >> 1, mf0 = (w & 1) * 2;
    const int pt = blockIdx.x;
    const int b = pt >> 4, r0 = (pt & 15) * 2;

    // ---- phase 0a: identity slab GEMM, B-frags from xpk (pure load+MFMA) ----
    if (w < 7) {
        const int spx = w * 32 + (l & 31);
        const int spxc = spx < 216 ? spx : 215;
        const int sr = spxc / 36, sc = spxc - sr * 36;
        const int r = r0 + sr - 2, cc = sc - 2;
        const bool valid = (spx < 216) && (r >= 0) && (r < 32) && (cc >= 0) && (cc < 32);
        const int rcl = min(max(r, 0), 31), ccl = min(max(cc, 0), 31);
        const int pcl = rcl * 32 + ccl;
        // per-lane xpk base: + kc*65536 walks kc; kh adds 32 bytes.
        const char* xb = (const char*)xpk + ((size_t)b * 1310720 + (size_t)pcl * 64 + ((l >> 5) * 16));

        f32x16 accI[2];
#pragma unroll
        for (int i = 0; i < 2; i++)
#pragma unroll
            for (int rr = 0; rr < 16; rr++) accI[i][rr] = 0.f;

        uint4 bq[2], bqn[2], av[2][2], avn[2][2];
#pragma unroll
        for (int kh = 0; kh < 2; kh++)
            bq[kh] = *(const uint4*)(xb + kh * 32);
#pragma unroll
        for (int mi2 = 0; mi2 < 2; mi2++)
#pragma unroll
            for (int kh = 0; kh < 2; kh++)
                av[mi2][kh] = ((const uint4*)wIt)[(mi2 << 7) + (kh << 6) + l];

        for (int kc = 0; kc < 20; kc++) {
            if (kc < 19) {
#pragma unroll
                for (int kh = 0; kh < 2; kh++)
                    bqn[kh] = *(const uint4*)(xb + (size_t)(kc + 1) * 65536 + kh * 32);
#pragma unroll
                for (int mi2 = 0; mi2 < 2; mi2++)
#pragma unroll
                    for (int kh = 0; kh < 2; kh++)
                        avn[mi2][kh] = ((const uint4*)wIt)[(kc + 1) * 256 + (mi2 << 7) + (kh << 6) + l];
            }
#pragma unroll
            for (int kh = 0; kh < 2; kh++) {
                accI[0] = __builtin_amdgcn_mfma_f32_32x32x16_bf16(*(short8*)&av[0][kh], *(short8*)&bq[kh], accI[0], 0, 0, 0);
                accI[1] = __builtin_amdgcn_mfma_f32_32x32x16_bf16(*(short8*)&av[1][kh], *(short8*)&bq[kh], accI[1], 0, 0, 0);
            }
            if (kc < 19) {
#pragma unroll
                for (int kh = 0; kh < 2; kh++) bq[kh] = bqn[kh];
#pragma unroll
                for (int mi2 = 0; mi2 < 2; mi2++)
#pragma unroll
                    for (int kh = 0; kh < 2; kh++) av[mi2][kh] = avn[mi2][kh];
            }
        }
        // bias + relu (in place), pixel L2-norm across 64 oc
        float ss = 0.f;
#pragma unroll
        for (int mi2 = 0; mi2 < 2; mi2++)
#pragma unroll
            for (int rg = 0; rg < 4; rg++) {
                float4 bb = *(const float4*)&biasI[mi2 * 32 + 8 * rg + 4 * (l >> 5)];
#pragma unroll
                for (int q = 0; q < 4; q++) {
                    float bv = (q == 0) ? bb.x : (q == 1) ? bb.y : (q == 2) ? bb.z : bb.w;
                    float t = fmaxf(accI[mi2][rg * 4 + q] + bv, 0.f);
                    accI[mi2][rg * 4 + q] = t;
                    ss = fmaf(t, t, ss);
                }
            }
        ss += __shfl_xor(ss, 32);        // lanes l and l+32 hold the same px
        float inv = 1.f / fmaxf(sqrtf(ss), 1e-12f);
        if (spx < 216) {
#pragma unroll
            for (int mi2 = 0; mi2 < 2; mi2++)
#pragma unroll
                for (int rg = 0; rg < 4; rg++) {
                    unsigned d0 = pack_bf16(accI[mi2][rg * 4 + 0] * inv, accI[mi2][rg * 4 + 1] * inv);
                    unsigned d1 = pack_bf16(accI[mi2][rg * 4 + 2] * inv, accI[mi2][rg * 4 + 3] * inv);
                    if (!valid) { d0 = 0u; d1 = 0u; }
                    *(uint2*)&slab[spx * 72 + mi2 * 32 + 8 * rg + 4 * (l >> 5)] = make_uint2(d0, d1);
                }
        }
    }
    __syncthreads();

    // ---- phase 0b: invD (featureL2Norm of corr) ----
    if (tid < 512) {
        int px = tid >> 3, part = tid & 7;
        int rh = px >> 5, rw = px & 31;
        float ctr[8];
        const unsigned* cp = (const unsigned*)&slab[((rh + 2) * 36 + rw + 2) * 72 + part * 8];
#pragma unroll
        for (int d = 0; d < 4; d++) { ctr[2 * d] = bflo(cp[d]); ctr[2 * d + 1] = bfhi(cp[d]); }
        float sum = 0.f;
#pragma unroll
        for (int k = 0; k < 25; k++) {
            const int kh = k / 5, kw = k % 5;
            const unsigned* nb = (const unsigned*)&slab[((rh + kh) * 36 + rw + kw) * 72 + part * 8];
#pragma unroll
            for (int d = 0; d < 4; d++) {
                float q0 = bflo(nb[d]) * ctr[2 * d];
                float q1 = bfhi(nb[d]) * ctr[2 * d + 1];
                sum = fmaf(q0, q0, sum); sum = fmaf(q1, q1, sum);
            }
        }
        sum += __shfl_xor(sum, 1);
        sum += __shfl_xor(sum, 2);
        sum += __shfl_xor(sum, 4);
        if (part == 0) invDs[px] = rsqrtf(sum + 1e-6f);
    }
    __syncthreads();

    // ---- phase 0c: normalized centers ----
    if (tid < 512) {
        int px = tid >> 3, q = tid & 7;
        int spx = ((px >> 5) + 2) * 36 + (px & 31) + 2;
        const unsigned* src = (const unsigned*)&slab[spx * 72 + q * 8];
        float iv = invDs[px];
        unsigned d[4];
#pragma unroll
        for (int dd = 0; dd < 4; dd++)
            d[dd] = pk_hu(bflo(src[dd]) * iv, bfhi(src[dd]) * iv);
        *(uint4*)&ctrs[px * 72 + q * 8] = make_uint4(d[0], d[1], d[2], d[3]);
    }
    __syncthreads();

    // ---- phase 1: emb GEMM, 8-kc chunks, rolling A/B prefetch ----
    const uint4* A = (const uint4*)wEt + (size_t)(mt * 52) * 512;

    f32x16 acc[2][2];
#pragma unroll
    for (int i = 0; i < 2; i++)
#pragma unroll
        for (int j = 0; j < 2; j++)
#pragma unroll
            for (int r = 0; r < 16; r++) acc[i][j][r] = 0.f;

    uint4 avc[2][2];
#pragma unroll
    for (int mi = 0; mi < 2; mi++)
#pragma unroll
        for (int kh = 0; kh < 2; kh++)
            avc[mi][kh] = A[(((mf0 + mi) * 2 + kh) << 6) + l];

    // gen chunk 0 (kc 0..7)
#pragma unroll
    for (int k = 0; k < 4; k++) {
        int u = tid + k * 640;
        if (u < 2048) {
            uint4 f = gen_feat_unit(slab, ctrs, (u >> 8), u & 255);
            *(uint4*)&stg[u * 16] = f;
        }
    }
    __syncthreads();

    uint4 bvc[2][2];
#pragma unroll
    for (int ni = 0; ni < 2; ni++)
#pragma unroll
        for (int kh = 0; kh < 2; kh++)
            bvc[ni][kh] = *(const uint4*)&stg[((ni << 7) + (kh << 6) + l) * 16];

#pragma unroll 1
    for (int c = 0; c < 6; c++) {
        const int cur = c & 1, nxt = cur ^ 1;
        const int base = c * 8;
        // generate next chunk into the free buffer (chunk c+1: 8 kc, last is 4)
        {
            const int nunits = (c < 5) ? 2048 : 1024;
            const int nbase = base + 8;
#pragma unroll
            for (int k = 0; k < 4; k++) {
                int u = tid + k * 640;
                if (u < nunits) {
                    uint4 f = gen_feat_unit(slab, ctrs, nbase + (u >> 8), u & 255);
                    *(uint4*)&stg[nxt * 32768 + u * 16] = f;
                }
            }
        }
#pragma unroll
        for (int kcL = 0; kcL < 8; kcL++) {
            const int kc = base + kcL;
            uint4 avn[2][2];
#pragma unroll
            for (int mi = 0; mi < 2; mi++)
#pragma unroll
                for (int kh = 0; kh < 2; kh++)
                    avn[mi][kh] = A[(size_t)(kc + 1) * 512 + (((mf0 + mi) * 2 + kh) << 6) + l];
            uint4 bvn[2][2];
            if (kcL < 7) {
#pragma unroll
                for (int ni = 0; ni < 2; ni++)
#pragma unroll
                    for (int kh = 0; kh < 2; kh++)
                        bvn[ni][kh] = *(const uint4*)&stg[cur * 32768 + ((kcL + 1) * 256 + (ni << 7) + (kh << 6) + l) * 16];
            }
#pragma unroll
            for (int kh = 0; kh < 2; kh++) {
                acc[0][0] = __builtin_amdgcn_mfma_f32_32x32x16_bf16(*(short8*)&avc[0][kh], *(short8*)&bvc[0][kh], acc[0][0], 0, 0, 0);
                acc[0][1] = __builtin_amdgcn_mfma_f32_32x32x16_bf16(*(short8*)&avc[0][kh], *(short8*)&bvc[1][kh], acc[0][1], 0, 0, 0);
                acc[1][0] = __builtin_amdgcn_mfma_f32_32x32x16_bf16(*(short8*)&avc[1][kh], *(short8*)&bvc[0][kh], acc[1][0], 0, 0, 0);
                acc[1][1] = __builtin_amdgcn_mfma_f32_32x32x16_bf16(*(short8*)&avc[1][kh], *(short8*)&bvc[1][kh], acc[1][1], 0, 0, 0);
            }
#pragma unroll
            for (int mi = 0; mi < 2; mi++)
#pragma unroll
                for (int kh = 0; kh < 2; kh++) avc[mi][kh] = avn[mi][kh];
            if (kcL < 7) {
#pragma unroll
                for (int ni = 0; ni < 2; ni++)
#pragma unroll
                    for (int kh = 0; kh < 2; kh++) bvc[ni][kh] = bvn[ni][kh];
            }
        }
        __syncthreads();
        // load first bv of next chunk from the buffer just generated
#pragma unroll
        for (int ni = 0; ni < 2; ni++)
#pragma unroll
            for (int kh = 0; kh < 2; kh++)
                bvc[ni][kh] = *(const uint4*)&stg[nxt * 32768 + ((ni << 7) + (kh << 6) + l) * 16];
    }
    // final chunk: kc 48..51, buffer index 6&1 = 0
#pragma unroll
    for (int kcL = 0; kcL < 4; kcL++) {
        const int kc = 48 + kcL;
        uint4 avn[2][2], bvn[2][2];
        if (kcL < 3) {
#pragma unroll
            for (int mi = 0; mi < 2; mi++)
#pragma unroll
                for (int kh = 0; kh < 2; kh++)
                    avn[mi][kh] = A[(size_t)(kc + 1) * 512 + (((mf0 + mi) * 2 + kh) << 6) + l];
#pragma unroll
            for (int ni = 0; ni < 2; ni++)
#pragma unroll
                for (int kh = 0; kh < 2; kh++)
                    bvn[ni][kh] = *(const uint4*)&stg[((kcL + 1) * 256 + (ni << 7) + (kh << 6) + l) * 16];
        }
#pragma unroll
        for (int kh = 0; kh < 2; kh++) {
            acc[0][0] = __builtin_amdgcn_mfma_f32_32x32x16_bf16(*(short8*)&avc[0][kh], *(short8*)&bvc[0][kh], acc[0][0], 0, 0, 0);
            acc[0][1] = __builtin_amdgcn_mfma_f32_32x32x16_bf16(*(short8*)&avc[0][kh], *(short8*)&bvc[1][kh], acc[0][1], 0, 0, 0);
            acc[1][0] = __builtin_amdgcn_mfma_f32_32x32x16_bf16(*(short8*)&avc[1][kh], *(short8*)&bvc[0][kh], acc[1][0], 0, 0, 0);
            acc[1][1] = __builtin_amdgcn_mfma_f32_32x32x16_bf16(*(short8*)&avc[1][kh], *(short8*)&bvc[1][kh], acc[1][1], 0, 0, 0);
        }
        if (kcL < 3) {
#pragma unroll
            for (int mi = 0; mi < 2; mi++)
#pragma unroll
                for (int kh = 0; kh < 2; kh++) avc[mi][kh] = avn[mi][kh];
#pragma unroll
            for (int ni = 0; ni < 2; ni++)
#pragma unroll
                for (int kh = 0; kh < 2; kh++) bvc[ni][kh] = bvn[ni][kh];
        }
    }
    __syncthreads();                     // all phase-1 LDS reads done: Ep may alias

    // ---- phase 2: bias+relu epilogue into Ep (out-GEMM B-frag order) ----
#pragma unroll
    for (int mi = 0; mi < 2; mi++) {
        const int kbase = (w * 2 + mi) * 256;
#pragma unroll
        for (int ni = 0; ni < 2; ni++) {
#pragma unroll
            for (int rg = 0; rg < 4; rg++) {
                int ocb = w * 64 + mi * 32 + 8 * rg + 4 * (l >> 5);
                float4 bb = *(const float4*)&biasE[ocb];
                unsigned d0 = pack_bf16(fmaxf(acc[mi][ni][rg * 4 + 0] + bb.x, 0.f),
                                        fmaxf(acc[mi][ni][rg * 4 + 1] + bb.y, 0.f));
                unsigned d1 = pack_bf16(fmaxf(acc[mi][ni][rg * 4 + 2] + bb.z, 0.f),
                                        fmaxf(acc[mi][ni][rg * 4 + 3] + bb.w, 0.f));
                int unit = kbase + (ni << 7) + ((rg >> 1) << 6) + ((rg & 1) << 5) + (l & 31);
                ((uint2*)Ep)[unit * 2 + (l >> 5)] = make_uint2(d0, d1);
            }
        }
    }
    __syncthreads();

    // ---- phase 3: out GEMM. B = Ep (LDS), A = wOt (L2), rolling prefetch ----
    const int p0 = pt * 64;
    const int hw0 = p0 & 1023;
    const uint4* Ao = (const uint4*)wOt + (size_t)(mt * 20) * 512;

    f32x16 acc2[2][2];
#pragma unroll
    for (int i = 0; i < 2; i++)
#pragma unroll
        for (int j = 0; j < 2; j++)
#pragma unroll
            for (int r = 0; r < 16; r++) acc2[i][j][r] = 0.f;

    uint4 aoc[2][2], boc[2][2];
#pragma unroll
    for (int mi = 0; mi < 2; mi++)
#pragma unroll
        for (int kh = 0; kh < 2; kh++)
            aoc[mi][kh] = Ao[(((mf0 + mi) * 2 + kh) << 6) + l];
#pragma unroll
    for (int ni = 0; ni < 2; ni++)
#pragma unroll
        for (int kh = 0; kh < 2; kh++)
            boc[ni][kh] = Ep[(ni << 7) + (kh << 6) + l];

#pragma unroll 4
    for (int kc = 0; kc < 20; kc++) {
        uint4 aon[2][2], bon[2][2];
        if (kc < 19) {
#pragma unroll
            for (int mi = 0; mi < 2; mi++)
#pragma unroll
                for (int kh = 0; kh < 2; kh++)
                    aon[mi][kh] = Ao[(size_t)(kc + 1) * 512 + (((mf0 + mi) * 2 + kh) << 6) + l];
#pragma unroll
            for (int ni = 0; ni < 2; ni++)
#pragma unroll
                for (int kh = 0; kh < 2; kh++)
                    bon[ni][kh] = Ep[(kc + 1) * 256 + (ni << 7) + (kh << 6) + l];
        }
#pragma unroll
        for (int kh = 0; kh < 2; kh++) {
            acc2[0][0] = __builtin_amdgcn_mfma_f32_32x32x16_bf16(*(short8*)&aoc[0][kh], *(short8*)&boc[0][kh], acc2[0][0], 0, 0, 0);
            acc2[0][1] = __builtin_amdgcn_mfma_f32_32x32x16_bf16(*(short8*)&aoc[0][kh], *(short8*)&boc[1][kh], acc2[0][1], 0, 0, 0);
            acc2[1][0] = __builtin_amdgcn_mfma_f32_32x32x16_bf16(*(short8*)&aoc[1][kh], *(short8*)&boc[0][kh], acc2[1][0], 0, 0, 0);
            acc2[1][1] = __builtin_amdgcn_mfma_f32_32x32x16_bf16(*(short8*)&aoc[1][kh], *(short8*)&boc[1][kh], acc2[1][1], 0, 0, 0);
        }
        if (kc < 19) {
#pragma unroll
            for (int mi = 0; mi < 2; mi++)
#pragma unroll
                for (int kh = 0; kh < 2; kh++) aoc[mi][kh] = aon[mi][kh];
#pragma unroll
            for (int ni = 0; ni < 2; ni++)
#pragma unroll
                for (int kh = 0; kh < 2; kh++) boc[ni][kh] = bon[ni][kh];
        }
    }

#pragma unroll
    for (int mi = 0; mi < 2; mi++)
#pragma unroll
        for (int ni = 0; ni < 2; ni++) {
            int pxl = ni * 32 + (l & 31);
#pragma unroll
            for (int r = 0; r < 16; r++) {
                int oc = w * 64 + mi * 32 + (r & 3) + 8 * (r >> 2) + 4 * (l >> 5);
                out[((size_t)b * 640 + oc) * 1024 + hw0 + pxl] = acc2[mi][ni][r] + biasO[oc];
            }
        }
}

// ===========================================================================
extern "C" void kernel_launch(void* const* d_in, const int* in_sizes, int n_in,
                              void* d_out, int out_size, void* d_ws, size_t ws_size,
                              hipStream_t stream)
{
    const float* x    = (const float*)d_in[0];
    const float* g1   = (const float*)d_in[1];
    const float* b1   = (const float*)d_in[2];
    const float* m1   = (const float*)d_in[3];
    const float* v1   = (const float*)d_in[4];
    const float* w_in = (const float*)d_in[5];
    const float* gi   = (const float*)d_in[6];
    const float* bi   = (const float*)d_in[7];
    const float* mi   = (const float*)d_in[8];
    const float* vi   = (const float*)d_in[9];
    const float* w_emb= (const float*)d_in[10];
    const float* ge   = (const float*)d_in[11];
    const float* be   = (const float*)d_in[12];
    const float* me   = (const float*)d_in[13];
    const float* ve   = (const float*)d_in[14];
    const float* w_out= (const float*)d_in[15];
    const float* go   = (const float*)d_in[16];
    const float* bo   = (const float*)d_in[17];
    const float* mo   = (const float*)d_in[18];
    const float* vo   = (const float*)d_in[19];

    char* ws = (char*)d_ws;
    float*    biasI = (float*)(ws + 5120);
    float*    biasE = (float*)(ws + 5376);
    float*    biasO = (float*)(ws + 7936);
    unsigned* wIt   = (unsigned*)(ws + 16384);
    unsigned* wOt   = (unsigned*)(ws + 98304);
    unsigned* wEt   = (unsigned*)(ws + 917504);    // ends 3,047,424
    unsigned* xpk   = (unsigned*)(ws + 3047424);   // 20,971,520 B -> ends 24,018,944
    float*    out   = (float*)d_out;

    k_prepAll<<<1192, 256, 0, stream>>>(x, g1, b1, m1, v1, w_in, gi, bi, mi, vi,
                                        w_emb, ge, be, me, ve, w_out, go, bo, mo, vo,
                                        biasI, biasE, biasO, wIt, wEt, wOt, xpk);
    k_mega<<<256, 640, 0, stream>>>(xpk, wIt, biasI,
                                    wEt, biasE, wOt, biasO, out);
}

// Round 10
// 192.487 us; speedup vs baseline: 1.0529x; 1.0529x over previous
//
#include <hip/hip_runtime.h>
#include <math.h>

#define BN_EPS 1e-5f

using short8  = __attribute__((ext_vector_type(8))) short;
using f32x16  = __attribute__((ext_vector_type(16))) float;

// ---------------------------------------------------------------------------
// x (16,640,32,32) fp32. Pixels P=16384, p = b*1024 + h*32 + w.
// feat K-order (permuted): kg'<64 -> identity ch kg'; kg'>=64: t=kg'-64,
//   ksp=t>>6 (spatial 0..24), c=t&63; orig w_emb col = 64 + c*25 + ksp.
// Weight tiles (A-frag order), per kc (K=32 chunk): see k_prepAll.
// xpk: bf16(relu(BN(x))) pre-packed for phase 0a:
//   byte ((b*20+kc)*1024 + p)*64 + o*16, o = octet: ch = kc*32 + o*8 + j.
//
// k_mega v3 (identity+feat+emb+out), one block per 64-px tile, 640 thr =
// 10 waves, wave w owns oc [64w,64w+64).
//  - phase 0a: pure load+MFMA (B-frags read from xpk; BN/relu/pack hoisted
//    to prepAll). 2 B-loads + 4 A-loads + 4 MFMA per kc, 1-ahead prefetch.
//  - phase 1: 8-kc chunks, rolling prefetch of next-kc A (L2) and B (LDS).
//  - phase 3: rolling prefetch of A and Ep fragments.
//  - LDS aliased: {slab|ctrs+invD+stg dbuf} reused as Ep. Peak 106112 B.
// prepAll xpk tail (r10): 1280 blocks (b x kc x quarter), per-block sc/bc
// in LDS computed ONCE (r9 recomputed them per pixel -> 22 us regression).
// ---------------------------------------------------------------------------

__device__ __forceinline__ float bflo(unsigned u) { return __uint_as_float(u << 16); }
__device__ __forceinline__ float bfhi(unsigned u) { return __uint_as_float(u & 0xffff0000u); }

__device__ __forceinline__ unsigned bf16_rne(float f) {
    unsigned u = __float_as_uint(f);
    return (u + 0x7fffu + ((u >> 16) & 1u)) >> 16;
}
__device__ __forceinline__ unsigned pack_bf16(float lo, float hi) {
    return bf16_rne(lo) | (bf16_rne(hi) << 16);
}
__device__ __forceinline__ unsigned pk_hu(float lo, float hi) {
    unsigned a = __float_as_uint(lo) + 0x8000u;
    unsigned b = __float_as_uint(hi) + 0x8000u;
    return __builtin_amdgcn_perm(b, a, 0x07060302u);
}
__device__ __forceinline__ unsigned pmul_fast(unsigned a, unsigned b) {
    return pk_hu(bflo(a) * bflo(b), bfhi(a) * bfhi(b));
}

// ===========================================================================
// k_prepAll: blocks [0,640) build wEt; blocks [640,872) scalars + wIt + wOt;
//            blocks [872,2152) build xpk = bf16(relu(BN(x))) in 0a B-order.
// ===========================================================================
__global__ __launch_bounds__(256)
void k_prepAll(const float* __restrict__ x,
               const float* __restrict__ g1, const float* __restrict__ b1,
               const float* __restrict__ m1, const float* __restrict__ v1,
               const float* __restrict__ w_in,
               const float* __restrict__ gi, const float* __restrict__ bi,
               const float* __restrict__ mi, const float* __restrict__ vi,
               const float* __restrict__ w_emb,
               const float* __restrict__ ge, const float* __restrict__ be,
               const float* __restrict__ me, const float* __restrict__ ve,
               const float* __restrict__ w_out,
               const float* __restrict__ go, const float* __restrict__ bo,
               const float* __restrict__ mo, const float* __restrict__ vo,
               float* __restrict__ biasI, float* __restrict__ biasE, float* __restrict__ biasO,
               unsigned* __restrict__ wIt, unsigned* __restrict__ wEt, unsigned* __restrict__ wOt,
               unsigned* __restrict__ xpk)
{
    __shared__ float row[1664];
    const int tid = threadIdx.x;

    if (blockIdx.x >= 872) {             // ---- xpk generation (1280 blocks) ----
        __shared__ float scb[64];        // [0,32) = sc, [32,64) = bc
        const int id2 = blockIdx.x - 872;
        const int b = id2 / 80;
        const int rem = id2 - b * 80;
        const int kc = rem >> 2, qr = rem & 3;
        const int p = qr * 256 + tid;
        if (tid < 64) {
            int ch = kc * 32 + (tid & 31);
            float s = g1[ch] * rsqrtf(v1[ch] + BN_EPS);
            scb[tid] = (tid < 32) ? s : (b1[ch] - m1[ch] * s);
        }
        __syncthreads();
        const float* xb = x + ((size_t)b * 640 + kc * 32) * 1024 + p;
        unsigned d[16];
#pragma unroll
        for (int j = 0; j < 16; j++) {
            float v0 = fmaxf(fmaf(xb[(size_t)(2 * j) * 1024],     scb[2 * j],     scb[32 + 2 * j]),     0.f);
            float v1_ = fmaxf(fmaf(xb[(size_t)(2 * j + 1) * 1024], scb[2 * j + 1], scb[32 + 2 * j + 1]), 0.f);
            d[j] = pack_bf16(v0, v1_);
        }
        char* dst = (char*)xpk + ((size_t)(b * 20 + kc) * 1024 + p) * 64;
#pragma unroll
        for (int o = 0; o < 4; o++)
            *(uint4*)(dst + o * 16) = make_uint4(d[4 * o], d[4 * o + 1], d[4 * o + 2], d[4 * o + 3]);
        return;
    }

    if (blockIdx.x < 640) {
        const int oc = blockIdx.x;
#pragma unroll
        for (int it = 0; it < 2; it++) {
            int u = it * 256 + tid;
            if (u < 416)
                ((float4*)row)[u] = ((const float4*)&w_emb[(size_t)oc * 1664])[u];
        }
        __syncthreads();
        if (tid < 208) {
            int kc = tid >> 2, kh = (tid >> 1) & 1, ksub = tid & 1;
            int k0 = kc * 32 + kh * 16 + ksub * 8;
            float sc = ge[oc] * rsqrtf(ve[oc] + BN_EPS);
            float v[8];
#pragma unroll
            for (int j = 0; j < 8; j++) {
                int kgp = k0 + j;
                int orig;
                if (kgp < 64) orig = kgp;
                else { int t = kgp - 64; orig = 64 + (t & 63) * 25 + (t >> 6); }
                v[j] = row[orig] * sc;
            }
            int mt = oc >> 7, mf = (oc >> 5) & 3;
            int idx = (mt * 52 + kc) * 512 + (mf * 2 + kh) * 64 + ksub * 32 + (oc & 31);
            ((uint4*)wEt)[idx] = make_uint4(pack_bf16(v[0], v[1]), pack_bf16(v[2], v[3]),
                                            pack_bf16(v[4], v[5]), pack_bf16(v[6], v[7]));
        }
        return;
    }

    int i = (blockIdx.x - 640) * 256 + tid;

    if (i < 64) {
        int c = i;
        float s = gi[c] * rsqrtf(vi[c] + BN_EPS);
        biasI[c] = bi[c] - mi[c] * s;
    } else if (i >= 704 && i < 1344) {
        int c = i - 704;
        float s = ge[c] * rsqrtf(ve[c] + BN_EPS);
        biasE[c] = be[c] - me[c] * s;
    } else if (i >= 1344 && i < 1984) {
        int c = i - 1344;
        float s = go[c] * rsqrtf(vo[c] + BN_EPS);
        biasO[c] = bo[c] - mo[c] * s;
    }

    if (i >= 2048 && i < 7168) {         // wIt
        int u = i - 2048;
        int kc = u >> 8, w = u & 255;
        int mf = w >> 7, kh = (w >> 6) & 1, sl = w & 63;
        int oc = mf * 32 + (sl & 31);
        int k0 = kc * 32 + kh * 16 + (sl >> 5) * 8;
        float sc = gi[oc] * rsqrtf(vi[oc] + BN_EPS);
        unsigned d[4];
#pragma unroll
        for (int q = 0; q < 4; q++)
            d[q] = pack_bf16(w_in[oc * 640 + k0 + 2 * q] * sc,
                             w_in[oc * 640 + k0 + 2 * q + 1] * sc);
        ((uint4*)wIt)[u] = make_uint4(d[0], d[1], d[2], d[3]);
    }

    if (i >= 8192 && i < 59392) {        // wOt
        int u = i - 8192;
        int ci = u >> 9, w = u & 511;
        int mt = ci / 20, kc = ci - mt * 20;
        int mf = w >> 7, kh = (w >> 6) & 1, sl = w & 63;
        int oc = mt * 128 + mf * 32 + (sl & 31);
        int k0 = kc * 32 + kh * 16 + (sl >> 5) * 8;
        float sc = go[oc] * rsqrtf(vo[oc] + BN_EPS);
        unsigned d[4];
#pragma unroll
        for (int q = 0; q < 4; q++)
            d[q] = pack_bf16(w_out[oc * 640 + k0 + 2 * q] * sc,
                             w_out[oc * 640 + k0 + 2 * q + 1] * sc);
        ((uint4*)wOt)[u] = make_uint4(d[0], d[1], d[2], d[3]);
    }
}

// ===========================================================================
// feat B-unit generator: unit (kcAbs, t) of the B-frag tile, from slab/ctrs.
// ===========================================================================
__device__ __forceinline__ uint4 gen_feat_unit(const short* slab, const short* ctrs,
                                               int kcAbs, int t)
{
    const int hf = t >> 7, sl = t & 63;
    const int bkh = (t >> 6) & 1;
    const int cl = bkh * 16 + (sl >> 5) * 8;
    if (kcAbs < 2) {
        int spxC = (hf + 2) * 36 + (sl & 31) + 2;
        return *(const uint4*)&slab[spxC * 72 + kcAbs * 32 + cl];
    } else {
        int pxl = hf * 32 + (sl & 31);
        int idx = kcAbs - 2;
        int ksp = idx >> 1;
        int cb = (idx & 1) * 32 + cl;
        int kho = ksp / 5, kwo = ksp - kho * 5;
        int spx = (hf + kho) * 36 + (sl & 31) + kwo;
        const unsigned* nb = (const unsigned*)&slab[spx * 72 + cb];
        const unsigned* ct = (const unsigned*)&ctrs[pxl * 72 + cb];
        return make_uint4(pmul_fast(nb[0], ct[0]), pmul_fast(nb[1], ct[1]),
                          pmul_fast(nb[2], ct[2]), pmul_fast(nb[3], ct[3]));
    }
}

// ===========================================================================
// k_mega v3: identity + feat + emb + out, one block per 64-px tile, 640 thr.
// LDS layout (106112 B total, aliased):
//   [0      , 31104) slab  (216 x 72 shorts)           -- phases 0a..1
//   [31104  , 40320) ctrs  (64 x 72 shorts)            -- phases 0c..1
//   [40320  , 40576) invD                               -- phase 0b..0c
//   [40576  , 106112) stg dbuf (2 x 32768 = 8 kc each)  -- phase 1
//   [0      ,  81920) Ep (20 kc x 256 uint4)            -- phases 2..3
// ===========================================================================
__global__ __launch_bounds__(640, 3)
void k_mega(const unsigned* __restrict__ xpk,
            const unsigned* __restrict__ wIt, const float* __restrict__ biasI,
            const unsigned* __restrict__ wEt, const float* __restrict__ biasE,
            const unsigned* __restrict__ wOt, const float* __restrict__ biasO,
            float* __restrict__ out)
{
    __shared__ __align__(16) char Lds[106112];
    short* slab  = (short*)Lds;
    short* ctrs  = (short*)(Lds + 31104);
    float* invDs = (float*)(Lds + 40320);
    char*  stg   = Lds + 40576;
    uint4* Ep    = (uint4*)Lds;

    const int tid = threadIdx.x;
    const int l = tid & 63;
    const int w = tid >> 6;              // wave 0..9, oc base = w*64
    const int mt = w >> 1, mf0 = (w & 1) * 2;
    const int pt = blockIdx.x;
    const int b = pt >> 4, r0 = (pt & 15) * 2;

    // ---- phase 0a: identity slab GEMM, B-frags from xpk (pure load+MFMA) ----
    if (w < 7) {
        const int spx = w * 32 + (l & 31);
        const int spxc = spx < 216 ? spx : 215;
        const int sr = spxc / 36, sc = spxc - sr * 36;
        const int r = r0 + sr - 2, cc = sc - 2;
        const bool valid = (spx < 216) && (r >= 0) && (r < 32) && (cc >= 0) && (cc < 32);
        const int rcl = min(max(r, 0), 31), ccl = min(max(cc, 0), 31);
        const int pcl = rcl * 32 + ccl;
        // per-lane xpk base: + kc*65536 walks kc; kh adds 32 bytes.
        const char* xb = (const char*)xpk + ((size_t)b * 1310720 + (size_t)pcl * 64 + ((l >> 5) * 16));

        f32x16 accI[2];
#pragma unroll
        for (int i = 0; i < 2; i++)
#pragma unroll
            for (int rr = 0; rr < 16; rr++) accI[i][rr] = 0.f;

        uint4 bq[2], bqn[2], av[2][2], avn[2][2];
#pragma unroll
        for (int kh = 0; kh < 2; kh++)
            bq[kh] = *(const uint4*)(xb + kh * 32);
#pragma unroll
        for (int mi2 = 0; mi2 < 2; mi2++)
#pragma unroll
            for (int kh = 0; kh < 2; kh++)
                av[mi2][kh] = ((const uint4*)wIt)[(mi2 << 7) + (kh << 6) + l];

        for (int kc = 0; kc < 20; kc++) {
            if (kc < 19) {
#pragma unroll
                for (int kh = 0; kh < 2; kh++)
                    bqn[kh] = *(const uint4*)(xb + (size_t)(kc + 1) * 65536 + kh * 32);
#pragma unroll
                for (int mi2 = 0; mi2 < 2; mi2++)
#pragma unroll
                    for (int kh = 0; kh < 2; kh++)
                        avn[mi2][kh] = ((const uint4*)wIt)[(kc + 1) * 256 + (mi2 << 7) + (kh << 6) + l];
            }
#pragma unroll
            for (int kh = 0; kh < 2; kh++) {
                accI[0] = __builtin_amdgcn_mfma_f32_32x32x16_bf16(*(short8*)&av[0][kh], *(short8*)&bq[kh], accI[0], 0, 0, 0);
                accI[1] = __builtin_amdgcn_mfma_f32_32x32x16_bf16(*(short8*)&av[1][kh], *(short8*)&bq[kh], accI[1], 0, 0, 0);
            }
            if (kc < 19) {
#pragma unroll
                for (int kh = 0; kh < 2; kh++) bq[kh] = bqn[kh];
#pragma unroll
                for (int mi2 = 0; mi2 < 2; mi2++)
#pragma unroll
                    for (int kh = 0; kh < 2; kh++) av[mi2][kh] = avn[mi2][kh];
            }
        }
        // bias + relu (in place), pixel L2-norm across 64 oc
        float ss = 0.f;
#pragma unroll
        for (int mi2 = 0; mi2 < 2; mi2++)
#pragma unroll
            for (int rg = 0; rg < 4; rg++) {
                float4 bb = *(const float4*)&biasI[mi2 * 32 + 8 * rg + 4 * (l >> 5)];
#pragma unroll
                for (int q = 0; q < 4; q++) {
                    float bv = (q == 0) ? bb.x : (q == 1) ? bb.y : (q == 2) ? bb.z : bb.w;
                    float t = fmaxf(accI[mi2][rg * 4 + q] + bv, 0.f);
                    accI[mi2][rg * 4 + q] = t;
                    ss = fmaf(t, t, ss);
                }
            }
        ss += __shfl_xor(ss, 32);        // lanes l and l+32 hold the same px
        float inv = 1.f / fmaxf(sqrtf(ss), 1e-12f);
        if (spx < 216) {
#pragma unroll
            for (int mi2 = 0; mi2 < 2; mi2++)
#pragma unroll
                for (int rg = 0; rg < 4; rg++) {
                    unsigned d0 = pack_bf16(accI[mi2][rg * 4 + 0] * inv, accI[mi2][rg * 4 + 1] * inv);
                    unsigned d1 = pack_bf16(accI[mi2][rg * 4 + 2] * inv, accI[mi2][rg * 4 + 3] * inv);
                    if (!valid) { d0 = 0u; d1 = 0u; }
                    *(uint2*)&slab[spx * 72 + mi2 * 32 + 8 * rg + 4 * (l >> 5)] = make_uint2(d0, d1);
                }
        }
    }
    __syncthreads();

    // ---- phase 0b: invD (featureL2Norm of corr) ----
    if (tid < 512) {
        int px = tid >> 3, part = tid & 7;
        int rh = px >> 5, rw = px & 31;
        float ctr[8];
        const unsigned* cp = (const unsigned*)&slab[((rh + 2) * 36 + rw + 2) * 72 + part * 8];
#pragma unroll
        for (int d = 0; d < 4; d++) { ctr[2 * d] = bflo(cp[d]); ctr[2 * d + 1] = bfhi(cp[d]); }
        float sum = 0.f;
#pragma unroll
        for (int k = 0; k < 25; k++) {
            const int kh = k / 5, kw = k % 5;
            const unsigned* nb = (const unsigned*)&slab[((rh + kh) * 36 + rw + kw) * 72 + part * 8];
#pragma unroll
            for (int d = 0; d < 4; d++) {
                float q0 = bflo(nb[d]) * ctr[2 * d];
                float q1 = bfhi(nb[d]) * ctr[2 * d + 1];
                sum = fmaf(q0, q0, sum); sum = fmaf(q1, q1, sum);
            }
        }
        sum += __shfl_xor(sum, 1);
        sum += __shfl_xor(sum, 2);
        sum += __shfl_xor(sum, 4);
        if (part == 0) invDs[px] = rsqrtf(sum + 1e-6f);
    }
    __syncthreads();

    // ---- phase 0c: normalized centers ----
    if (tid < 512) {
        int px = tid >> 3, q = tid & 7;
        int spx = ((px >> 5) + 2) * 36 + (px & 31) + 2;
        const unsigned* src = (const unsigned*)&slab[spx * 72 + q * 8];
        float iv = invDs[px];
        unsigned d[4];
#pragma unroll
        for (int dd = 0; dd < 4; dd++)
            d[dd] = pk_hu(bflo(src[dd]) * iv, bfhi(src[dd]) * iv);
        *(uint4*)&ctrs[px * 72 + q * 8] = make_uint4(d[0], d[1], d[2], d[3]);
    }
    __syncthreads();

    // ---- phase 1: emb GEMM, 8-kc chunks, rolling A/B prefetch ----
    const uint4* A = (const uint4*)wEt + (size_t)(mt * 52) * 512;

    f32x16 acc[2][2];
#pragma unroll
    for (int i = 0; i < 2; i++)
#pragma unroll
        for (int j = 0; j < 2; j++)
#pragma unroll
            for (int r = 0; r < 16; r++) acc[i][j][r] = 0.f;

    uint4 avc[2][2];
#pragma unroll
    for (int mi = 0; mi < 2; mi++)
#pragma unroll
        for (int kh = 0; kh < 2; kh++)
            avc[mi][kh] = A[(((mf0 + mi) * 2 + kh) << 6) + l];

    // gen chunk 0 (kc 0..7)
#pragma unroll
    for (int k = 0; k < 4; k++) {
        int u = tid + k * 640;
        if (u < 2048) {
            uint4 f = gen_feat_unit(slab, ctrs, (u >> 8), u & 255);
            *(uint4*)&stg[u * 16] = f;
        }
    }
    __syncthreads();

    uint4 bvc[2][2];
#pragma unroll
    for (int ni = 0; ni < 2; ni++)
#pragma unroll
        for (int kh = 0; kh < 2; kh++)
            bvc[ni][kh] = *(const uint4*)&stg[((ni << 7) + (kh << 6) + l) * 16];

#pragma unroll 1
    for (int c = 0; c < 6; c++) {
        const int cur = c & 1, nxt = cur ^ 1;
        const int base = c * 8;
        // generate next chunk into the free buffer (chunk c+1: 8 kc, last is 4)
        {
            const int nunits = (c < 5) ? 2048 : 1024;
            const int nbase = base + 8;
#pragma unroll
            for (int k = 0; k < 4; k++) {
                int u = tid + k * 640;
                if (u < nunits) {
                    uint4 f = gen_feat_unit(slab, ctrs, nbase + (u >> 8), u & 255);
                    *(uint4*)&stg[nxt * 32768 + u * 16] = f;
                }
            }
        }
#pragma unroll
        for (int kcL = 0; kcL < 8; kcL++) {
            const int kc = base + kcL;
            uint4 avn[2][2];
#pragma unroll
            for (int mi = 0; mi < 2; mi++)
#pragma unroll
                for (int kh = 0; kh < 2; kh++)
                    avn[mi][kh] = A[(size_t)(kc + 1) * 512 + (((mf0 + mi) * 2 + kh) << 6) + l];
            uint4 bvn[2][2];
            if (kcL < 7) {
#pragma unroll
                for (int ni = 0; ni < 2; ni++)
#pragma unroll
                    for (int kh = 0; kh < 2; kh++)
                        bvn[ni][kh] = *(const uint4*)&stg[cur * 32768 + ((kcL + 1) * 256 + (ni << 7) + (kh << 6) + l) * 16];
            }
#pragma unroll
            for (int kh = 0; kh < 2; kh++) {
                acc[0][0] = __builtin_amdgcn_mfma_f32_32x32x16_bf16(*(short8*)&avc[0][kh], *(short8*)&bvc[0][kh], acc[0][0], 0, 0, 0);
                acc[0][1] = __builtin_amdgcn_mfma_f32_32x32x16_bf16(*(short8*)&avc[0][kh], *(short8*)&bvc[1][kh], acc[0][1], 0, 0, 0);
                acc[1][0] = __builtin_amdgcn_mfma_f32_32x32x16_bf16(*(short8*)&avc[1][kh], *(short8*)&bvc[0][kh], acc[1][0], 0, 0, 0);
                acc[1][1] = __builtin_amdgcn_mfma_f32_32x32x16_bf16(*(short8*)&avc[1][kh], *(short8*)&bvc[1][kh], acc[1][1], 0, 0, 0);
            }
#pragma unroll
            for (int mi = 0; mi < 2; mi++)
#pragma unroll
                for (int kh = 0; kh < 2; kh++) avc[mi][kh] = avn[mi][kh];
            if (kcL < 7) {
#pragma unroll
                for (int ni = 0; ni < 2; ni++)
#pragma unroll
                    for (int kh = 0; kh < 2; kh++) bvc[ni][kh] = bvn[ni][kh];
            }
        }
        __syncthreads();
        // load first bv of next chunk from the buffer just generated
#pragma unroll
        for (int ni = 0; ni < 2; ni++)
#pragma unroll
            for (int kh = 0; kh < 2; kh++)
                bvc[ni][kh] = *(const uint4*)&stg[nxt * 32768 + ((ni << 7) + (kh << 6) + l) * 16];
    }
    // final chunk: kc 48..51, buffer index 6&1 = 0
#pragma unroll
    for (int kcL = 0; kcL < 4; kcL++) {
        const int kc = 48 + kcL;
        uint4 avn[2][2], bvn[2][2];
        if (kcL < 3) {
#pragma unroll
            for (int mi = 0; mi < 2; mi++)
#pragma unroll
                for (int kh = 0; kh < 2; kh++)
                    avn[mi][kh] = A[(size_t)(kc + 1) * 512 + (((mf0 + mi) * 2 + kh) << 6) + l];
#pragma unroll
            for (int ni = 0; ni < 2; ni++)
#pragma unroll
                for (int kh = 0; kh < 2; kh++)
                    bvn[ni][kh] = *(const uint4*)&stg[((kcL + 1) * 256 + (ni << 7) + (kh << 6) + l) * 16];
        }
#pragma unroll
        for (int kh = 0; kh < 2; kh++) {
            acc[0][0] = __builtin_amdgcn_mfma_f32_32x32x16_bf16(*(short8*)&avc[0][kh], *(short8*)&bvc[0][kh], acc[0][0], 0, 0, 0);
            acc[0][1] = __builtin_amdgcn_mfma_f32_32x32x16_bf16(*(short8*)&avc[0][kh], *(short8*)&bvc[1][kh], acc[0][1], 0, 0, 0);
            acc[1][0] = __builtin_amdgcn_mfma_f32_32x32x16_bf16(*(short8*)&avc[1][kh], *(short8*)&bvc[0][kh], acc[1][0], 0, 0, 0);
            acc[1][1] = __builtin_amdgcn_mfma_f32_32x32x16_bf16(*(short8*)&avc[1][kh], *(short8*)&bvc[1][kh], acc[1][1], 0, 0, 0);
        }
        if (kcL < 3) {
#pragma unroll
            for (int mi = 0; mi < 2; mi++)
#pragma unroll
                for (int kh = 0; kh < 2; kh++) avc[mi][kh] = avn[mi][kh];
#pragma unroll
            for (int ni = 0; ni < 2; ni++)
#pragma unroll
                for (int kh = 0; kh < 2; kh++) bvc[ni][kh] = bvn[ni][kh];
        }
    }
    __syncthreads();                     // all phase-1 LDS reads done: Ep may alias

    // ---- phase 2: bias+relu epilogue into Ep (out-GEMM B-frag order) ----
#pragma unroll
    for (int mi = 0; mi < 2; mi++) {
        const int kbase = (w * 2 + mi) * 256;
#pragma unroll
        for (int ni = 0; ni < 2; ni++) {
#pragma unroll
            for (int rg = 0; rg < 4; rg++) {
                int ocb = w * 64 + mi * 32 + 8 * rg + 4 * (l >> 5);
                float4 bb = *(const float4*)&biasE[ocb];
                unsigned d0 = pack_bf16(fmaxf(acc[mi][ni][rg * 4 + 0] + bb.x, 0.f),
                                        fmaxf(acc[mi][ni][rg * 4 + 1] + bb.y, 0.f));
                unsigned d1 = pack_bf16(fmaxf(acc[mi][ni][rg * 4 + 2] + bb.z, 0.f),
                                        fmaxf(acc[mi][ni][rg * 4 + 3] + bb.w, 0.f));
                int unit = kbase + (ni << 7) + ((rg >> 1) << 6) + ((rg & 1) << 5) + (l & 31);
                ((uint2*)Ep)[unit * 2 + (l >> 5)] = make_uint2(d0, d1);
            }
        }
    }
    __syncthreads();

    // ---- phase 3: out GEMM. B = Ep (LDS), A = wOt (L2), rolling prefetch ----
    const int p0 = pt * 64;
    const int hw0 = p0 & 1023;
    const uint4* Ao = (const uint4*)wOt + (size_t)(mt * 20) * 512;

    f32x16 acc2[2][2];
#pragma unroll
    for (int i = 0; i < 2; i++)
#pragma unroll
        for (int j = 0; j < 2; j++)
#pragma unroll
            for (int r = 0; r < 16; r++) acc2[i][j][r] = 0.f;

    uint4 aoc[2][2], boc[2][2];
#pragma unroll
    for (int mi = 0; mi < 2; mi++)
#pragma unroll
        for (int kh = 0; kh < 2; kh++)
            aoc[mi][kh] = Ao[(((mf0 + mi) * 2 + kh) << 6) + l];
#pragma unroll
    for (int ni = 0; ni < 2; ni++)
#pragma unroll
        for (int kh = 0; kh < 2; kh++)
            boc[ni][kh] = Ep[(ni << 7) + (kh << 6) + l];

#pragma unroll 4
    for (int kc = 0; kc < 20; kc++) {
        uint4 aon[2][2], bon[2][2];
        if (kc < 19) {
#pragma unroll
            for (int mi = 0; mi < 2; mi++)
#pragma unroll
                for (int kh = 0; kh < 2; kh++)
                    aon[mi][kh] = Ao[(size_t)(kc + 1) * 512 + (((mf0 + mi) * 2 + kh) << 6) + l];
#pragma unroll
            for (int ni = 0; ni < 2; ni++)
#pragma unroll
                for (int kh = 0; kh < 2; kh++)
                    bon[ni][kh] = Ep[(kc + 1) * 256 + (ni << 7) + (kh << 6) + l];
        }
#pragma unroll
        for (int kh = 0; kh < 2; kh++) {
            acc2[0][0] = __builtin_amdgcn_mfma_f32_32x32x16_bf16(*(short8*)&aoc[0][kh], *(short8*)&boc[0][kh], acc2[0][0], 0, 0, 0);
            acc2[0][1] = __builtin_amdgcn_mfma_f32_32x32x16_bf16(*(short8*)&aoc[0][kh], *(short8*)&boc[1][kh], acc2[0][1], 0, 0, 0);
            acc2[1][0] = __builtin_amdgcn_mfma_f32_32x32x16_bf16(*(short8*)&aoc[1][kh], *(short8*)&boc[0][kh], acc2[1][0], 0, 0, 0);
            acc2[1][1] = __builtin_amdgcn_mfma_f32_32x32x16_bf16(*(short8*)&aoc[1][kh], *(short8*)&boc[1][kh], acc2[1][1], 0, 0, 0);
        }
        if (kc < 19) {
#pragma unroll
            for (int mi = 0; mi < 2; mi++)
#pragma unroll
                for (int kh = 0; kh < 2; kh++) aoc[mi][kh] = aon[mi][kh];
#pragma unroll
            for (int ni = 0; ni < 2; ni++)
#pragma unroll
                for (int kh = 0; kh < 2; kh++) boc[ni][kh] = bon[ni][kh];
        }
    }

#pragma unroll
    for (int mi = 0; mi < 2; mi++)
#pragma unroll
        for (int ni = 0; ni < 2; ni++) {
            int pxl = ni * 32 + (l & 31);
#pragma unroll
            for (int r = 0; r < 16; r++) {
                int oc = w * 64 + mi * 32 + (r & 3) + 8 * (r >> 2) + 4 * (l >> 5);
                out[((size_t)b * 640 + oc) * 1024 + hw0 + pxl] = acc2[mi][ni][r] + biasO[oc];
            }
        }
}

// ===========================================================================
extern "C" void kernel_launch(void* const* d_in, const int* in_sizes, int n_in,
                              void* d_out, int out_size, void* d_ws, size_t ws_size,
                              hipStream_t stream)
{
    const float* x    = (const float*)d_in[0];
    const float* g1   = (const float*)d_in[1];
    const float* b1   = (const float*)d_in[2];
    const float* m1   = (const float*)d_in[3];
    const float* v1   = (const float*)d_in[4];
    const float* w_in = (const float*)d_in[5];
    const float* gi   = (const float*)d_in[6];
    const float* bi   = (const float*)d_in[7];
    const float* mi   = (const float*)d_in[8];
    const float* vi   = (const float*)d_in[9];
    const float* w_emb= (const float*)d_in[10];
    const float* ge   = (const float*)d_in[11];
    const float* be   = (const float*)d_in[12];
    const float* me   = (const float*)d_in[13];
    const float* ve   = (const float*)d_in[14];
    const float* w_out= (const float*)d_in[15];
    const float* go   = (const float*)d_in[16];
    const float* bo   = (const float*)d_in[17];
    const float* mo   = (const float*)d_in[18];
    const float* vo   = (const float*)d_in[19];

    char* ws = (char*)d_ws;
    float*    biasI = (float*)(ws + 5120);
    float*    biasE = (float*)(ws + 5376);
    float*    biasO = (float*)(ws + 7936);
    unsigned* wIt   = (unsigned*)(ws + 16384);
    unsigned* wOt   = (unsigned*)(ws + 98304);
    unsigned* wEt   = (unsigned*)(ws + 917504);    // ends 3,047,424
    unsigned* xpk   = (unsigned*)(ws + 3047424);   // 20,971,520 B -> ends 24,018,944
    float*    out   = (float*)d_out;

    k_prepAll<<<2152, 256, 0, stream>>>(x, g1, b1, m1, v1, w_in, gi, bi, mi, vi,
                                        w_emb, ge, be, me, ve, w_out, go, bo, mo, vo,
                                        biasI, biasE, biasO, wIt, wEt, wOt, xpk);
    k_mega<<<256, 640, 0, stream>>>(xpk, wIt, biasI,
                                    wEt, biasE, wOt, biasO, out);
}

// Round 11
// 190.016 us; speedup vs baseline: 1.0666x; 1.0130x over previous
//
#include <hip/hip_runtime.h>
#include <math.h>

#define BN_EPS 1e-5f

using short8  = __attribute__((ext_vector_type(8))) short;
using f32x16  = __attribute__((ext_vector_type(16))) float;

// ---------------------------------------------------------------------------
// x (16,640,32,32) fp32. Pixels P=16384, p = b*1024 + h*32 + w.
// feat K-order (permuted): kg'<64 -> identity ch kg'; kg'>=64: t=kg'-64,
//   ksp=t>>6 (spatial 0..24), c=t&63; orig w_emb col = 64 + c*25 + ksp.
// Weight tiles (A-frag order), per kc (K=32 chunk): see k_prepAll.
// xpk: bf16(relu(BN(x))) pre-packed for phase 0a:
//   byte ((b*20+kc)*1024 + p)*64 + o*16, o = octet: ch = kc*32 + o*8 + j.
//
// k_mega v4 (identity+feat+emb+out), one block per 64-px tile, 640 thr =
// 10 waves, wave w owns oc [64w,64w+64).
//  - XCD-chunked blockIdx remap: pt = (bx&7)*32 + (bx>>3); 32 consecutive
//    tiles (2 images, 2.6 MB xpk slice < 4MB L2) per XCD -> halo re-reads
//    of xpk become L2 hits (were cross-XCD L3/HBM misses, FETCH 2x xpk).
//  - phase 0a: pure load+MFMA, B from xpk with 2-DEEP prefetch (L3-latency
//    cover); A from wIt 1-deep (L2).
//  - phase 1: 8-kc chunks, rolling prefetch of next-kc A (L2) and B (LDS).
//  - phase 3: rolling prefetch of A and Ep fragments.
//  - LDS aliased: {slab|ctrs+invD+stg dbuf} reused as Ep. Peak 106112 B.
// prepAll wEt (r11): 80 blocks x 8 oc (linear 53KB stage + hoisted scales);
// was 640 tiny blocks (~1 useful wave each, ~8 us of launch/latency waste).
// ---------------------------------------------------------------------------

__device__ __forceinline__ float bflo(unsigned u) { return __uint_as_float(u << 16); }
__device__ __forceinline__ float bfhi(unsigned u) { return __uint_as_float(u & 0xffff0000u); }

__device__ __forceinline__ unsigned bf16_rne(float f) {
    unsigned u = __float_as_uint(f);
    return (u + 0x7fffu + ((u >> 16) & 1u)) >> 16;
}
__device__ __forceinline__ unsigned pack_bf16(float lo, float hi) {
    return bf16_rne(lo) | (bf16_rne(hi) << 16);
}
__device__ __forceinline__ unsigned pk_hu(float lo, float hi) {
    unsigned a = __float_as_uint(lo) + 0x8000u;
    unsigned b = __float_as_uint(hi) + 0x8000u;
    return __builtin_amdgcn_perm(b, a, 0x07060302u);
}
__device__ __forceinline__ unsigned pmul_fast(unsigned a, unsigned b) {
    return pk_hu(bflo(a) * bflo(b), bfhi(a) * bfhi(b));
}

// ===========================================================================
// k_prepAll: blocks [0,80) build wEt (8 oc each); [80,312) scalars+wIt+wOt;
//            [312,1592) build xpk = bf16(relu(BN(x))) in 0a B-order.
// ===========================================================================
__global__ __launch_bounds__(256)
void k_prepAll(const float* __restrict__ x,
               const float* __restrict__ g1, const float* __restrict__ b1,
               const float* __restrict__ m1, const float* __restrict__ v1,
               const float* __restrict__ w_in,
               const float* __restrict__ gi, const float* __restrict__ bi,
               const float* __restrict__ mi, const float* __restrict__ vi,
               const float* __restrict__ w_emb,
               const float* __restrict__ ge, const float* __restrict__ be,
               const float* __restrict__ me, const float* __restrict__ ve,
               const float* __restrict__ w_out,
               const float* __restrict__ go, const float* __restrict__ bo,
               const float* __restrict__ mo, const float* __restrict__ vo,
               float* __restrict__ biasI, float* __restrict__ biasE, float* __restrict__ biasO,
               unsigned* __restrict__ wIt, unsigned* __restrict__ wEt, unsigned* __restrict__ wOt,
               unsigned* __restrict__ xpk)
{
    const int tid = threadIdx.x;

    if (blockIdx.x >= 312) {             // ---- xpk generation (1280 blocks) ----
        __shared__ float scb[64];        // [0,32) = sc, [32,64) = bc
        const int id2 = blockIdx.x - 312;
        const int b = id2 / 80;
        const int rem = id2 - b * 80;
        const int kc = rem >> 2, qr = rem & 3;
        const int p = qr * 256 + tid;
        if (tid < 64) {
            int ch = kc * 32 + (tid & 31);
            float s = g1[ch] * rsqrtf(v1[ch] + BN_EPS);
            scb[tid] = (tid < 32) ? s : (b1[ch] - m1[ch] * s);
        }
        __syncthreads();
        const float* xb = x + ((size_t)b * 640 + kc * 32) * 1024 + p;
        unsigned d[16];
#pragma unroll
        for (int j = 0; j < 16; j++) {
            float v0 = fmaxf(fmaf(xb[(size_t)(2 * j) * 1024],     scb[2 * j],     scb[32 + 2 * j]),     0.f);
            float v1_ = fmaxf(fmaf(xb[(size_t)(2 * j + 1) * 1024], scb[2 * j + 1], scb[32 + 2 * j + 1]), 0.f);
            d[j] = pack_bf16(v0, v1_);
        }
        char* dst = (char*)xpk + ((size_t)(b * 20 + kc) * 1024 + p) * 64;
#pragma unroll
        for (int o = 0; o < 4; o++)
            *(uint4*)(dst + o * 16) = make_uint4(d[4 * o], d[4 * o + 1], d[4 * o + 2], d[4 * o + 3]);
        return;
    }

    if (blockIdx.x < 80) {               // ---- wEt: 8 oc per block ----
        __shared__ float rows[8 * 1664]; // 53248 B, contiguous rows of w_emb
        __shared__ float scs[8];
        const int oc0 = blockIdx.x * 8;
#pragma unroll
        for (int it = 0; it < 13; it++) {
            int u = it * 256 + tid;
            if (u < 3328)
                ((float4*)rows)[u] = ((const float4*)w_emb)[(size_t)oc0 * 416 + u];
        }
        if (tid < 8) {
            int oc = oc0 + tid;
            scs[tid] = ge[oc] * rsqrtf(ve[oc] + BN_EPS);
        }
        __syncthreads();
#pragma unroll
        for (int it = 0; it < 7; it++) {
            int t = it * 256 + tid;
            if (t < 1664) {
                int ocl = t / 208, sub = t - ocl * 208;
                int oc = oc0 + ocl;
                int kc = sub >> 2, kh = (sub >> 1) & 1, ksub = sub & 1;
                int k0 = kc * 32 + kh * 16 + ksub * 8;
                float sc = scs[ocl];
                const float* row = &rows[ocl * 1664];
                float v[8];
#pragma unroll
                for (int j = 0; j < 8; j++) {
                    int kgp = k0 + j;
                    int orig;
                    if (kgp < 64) orig = kgp;
                    else { int tt = kgp - 64; orig = 64 + (tt & 63) * 25 + (tt >> 6); }
                    v[j] = row[orig] * sc;
                }
                int mt = oc >> 7, mf = (oc >> 5) & 3;
                int idx = (mt * 52 + kc) * 512 + (mf * 2 + kh) * 64 + ksub * 32 + (oc & 31);
                ((uint4*)wEt)[idx] = make_uint4(pack_bf16(v[0], v[1]), pack_bf16(v[2], v[3]),
                                                pack_bf16(v[4], v[5]), pack_bf16(v[6], v[7]));
            }
        }
        return;
    }

    int i = (blockIdx.x - 80) * 256 + tid;

    if (i < 64) {
        int c = i;
        float s = gi[c] * rsqrtf(vi[c] + BN_EPS);
        biasI[c] = bi[c] - mi[c] * s;
    } else if (i >= 704 && i < 1344) {
        int c = i - 704;
        float s = ge[c] * rsqrtf(ve[c] + BN_EPS);
        biasE[c] = be[c] - me[c] * s;
    } else if (i >= 1344 && i < 1984) {
        int c = i - 1344;
        float s = go[c] * rsqrtf(vo[c] + BN_EPS);
        biasO[c] = bo[c] - mo[c] * s;
    }

    if (i >= 2048 && i < 7168) {         // wIt
        int u = i - 2048;
        int kc = u >> 8, w = u & 255;
        int mf = w >> 7, kh = (w >> 6) & 1, sl = w & 63;
        int oc = mf * 32 + (sl & 31);
        int k0 = kc * 32 + kh * 16 + (sl >> 5) * 8;
        float sc = gi[oc] * rsqrtf(vi[oc] + BN_EPS);
        unsigned d[4];
#pragma unroll
        for (int q = 0; q < 4; q++)
            d[q] = pack_bf16(w_in[oc * 640 + k0 + 2 * q] * sc,
                             w_in[oc * 640 + k0 + 2 * q + 1] * sc);
        ((uint4*)wIt)[u] = make_uint4(d[0], d[1], d[2], d[3]);
    }

    if (i >= 8192 && i < 59392) {        // wOt
        int u = i - 8192;
        int ci = u >> 9, w = u & 511;
        int mt = ci / 20, kc = ci - mt * 20;
        int mf = w >> 7, kh = (w >> 6) & 1, sl = w & 63;
        int oc = mt * 128 + mf * 32 + (sl & 31);
        int k0 = kc * 32 + kh * 16 + (sl >> 5) * 8;
        float sc = go[oc] * rsqrtf(vo[oc] + BN_EPS);
        unsigned d[4];
#pragma unroll
        for (int q = 0; q < 4; q++)
            d[q] = pack_bf16(w_out[oc * 640 + k0 + 2 * q] * sc,
                             w_out[oc * 640 + k0 + 2 * q + 1] * sc);
        ((uint4*)wOt)[u] = make_uint4(d[0], d[1], d[2], d[3]);
    }
}

// ===========================================================================
// feat B-unit generator: unit (kcAbs, t) of the B-frag tile, from slab/ctrs.
// ===========================================================================
__device__ __forceinline__ uint4 gen_feat_unit(const short* slab, const short* ctrs,
                                               int kcAbs, int t)
{
    const int hf = t >> 7, sl = t & 63;
    const int bkh = (t >> 6) & 1;
    const int cl = bkh * 16 + (sl >> 5) * 8;
    if (kcAbs < 2) {
        int spxC = (hf + 2) * 36 + (sl & 31) + 2;
        return *(const uint4*)&slab[spxC * 72 + kcAbs * 32 + cl];
    } else {
        int pxl = hf * 32 + (sl & 31);
        int idx = kcAbs - 2;
        int ksp = idx >> 1;
        int cb = (idx & 1) * 32 + cl;
        int kho = ksp / 5, kwo = ksp - kho * 5;
        int spx = (hf + kho) * 36 + (sl & 31) + kwo;
        const unsigned* nb = (const unsigned*)&slab[spx * 72 + cb];
        const unsigned* ct = (const unsigned*)&ctrs[pxl * 72 + cb];
        return make_uint4(pmul_fast(nb[0], ct[0]), pmul_fast(nb[1], ct[1]),
                          pmul_fast(nb[2], ct[2]), pmul_fast(nb[3], ct[3]));
    }
}

// ===========================================================================
// k_mega v4: identity + feat + emb + out, one block per 64-px tile, 640 thr.
// LDS layout (106112 B total, aliased):
//   [0      , 31104) slab  (216 x 72 shorts)           -- phases 0a..1
//   [31104  , 40320) ctrs  (64 x 72 shorts)            -- phases 0c..1
//   [40320  , 40576) invD                               -- phase 0b..0c
//   [40576  , 106112) stg dbuf (2 x 32768 = 8 kc each)  -- phase 1
//   [0      ,  81920) Ep (20 kc x 256 uint4)            -- phases 2..3
// ===========================================================================
__global__ __launch_bounds__(640, 3)
void k_mega(const unsigned* __restrict__ xpk,
            const unsigned* __restrict__ wIt, const float* __restrict__ biasI,
            const unsigned* __restrict__ wEt, const float* __restrict__ biasE,
            const unsigned* __restrict__ wOt, const float* __restrict__ biasO,
            float* __restrict__ out)
{
    __shared__ __align__(16) char Lds[106112];
    short* slab  = (short*)Lds;
    short* ctrs  = (short*)(Lds + 31104);
    float* invDs = (float*)(Lds + 40320);
    char*  stg   = Lds + 40576;
    uint4* Ep    = (uint4*)Lds;

    const int tid = threadIdx.x;
    const int l = tid & 63;
    const int w = tid >> 6;              // wave 0..9, oc base = w*64
    const int mt = w >> 1, mf0 = (w & 1) * 2;
    // XCD-chunked remap: dispatch round-robins XCDs by blockIdx%8, so this
    // gives each XCD 32 consecutive tiles (2 images; xpk slice L2-resident).
    const int bx = blockIdx.x;
    const int pt = ((bx & 7) << 5) | (bx >> 3);
    const int b = pt >> 4, r0 = (pt & 15) * 2;

    // ---- phase 0a: identity slab GEMM, B from xpk, 2-deep B prefetch ----
    if (w < 7) {
        const int spx = w * 32 + (l & 31);
        const int spxc = spx < 216 ? spx : 215;
        const int sr = spxc / 36, sc = spxc - sr * 36;
        const int r = r0 + sr - 2, cc = sc - 2;
        const bool valid = (spx < 216) && (r >= 0) && (r < 32) && (cc >= 0) && (cc < 32);
        const int rcl = min(max(r, 0), 31), ccl = min(max(cc, 0), 31);
        const int pcl = rcl * 32 + ccl;
        // per-lane xpk base: + kc*65536 walks kc; kh adds 32 bytes.
        const char* xb = (const char*)xpk + ((size_t)b * 1310720 + (size_t)pcl * 64 + ((l >> 5) * 16));

        f32x16 accI[2];
#pragma unroll
        for (int i = 0; i < 2; i++)
#pragma unroll
            for (int rr = 0; rr < 16; rr++) accI[i][rr] = 0.f;

        uint4 bq0[2], bq1[2], avA[2][2], avB[2][2];
#pragma unroll
        for (int kh = 0; kh < 2; kh++) {
            bq0[kh] = *(const uint4*)(xb + kh * 32);
            bq1[kh] = *(const uint4*)(xb + 65536 + kh * 32);
        }
#pragma unroll
        for (int mi2 = 0; mi2 < 2; mi2++)
#pragma unroll
            for (int kh = 0; kh < 2; kh++)
                avA[mi2][kh] = ((const uint4*)wIt)[(mi2 << 7) + (kh << 6) + l];

#pragma unroll 1
        for (int kc2 = 0; kc2 < 10; kc2++) {
            const int kc = kc2 * 2;
            // A(kc+1) -> avB (L2, 1-deep)
#pragma unroll
            for (int mi2 = 0; mi2 < 2; mi2++)
#pragma unroll
                for (int kh = 0; kh < 2; kh++)
                    avB[mi2][kh] = ((const uint4*)wIt)[(kc + 1) * 256 + (mi2 << 7) + (kh << 6) + l];
            // MFMA kc
#pragma unroll
            for (int kh = 0; kh < 2; kh++) {
                accI[0] = __builtin_amdgcn_mfma_f32_32x32x16_bf16(*(short8*)&avA[0][kh], *(short8*)&bq0[kh], accI[0], 0, 0, 0);
                accI[1] = __builtin_amdgcn_mfma_f32_32x32x16_bf16(*(short8*)&avA[1][kh], *(short8*)&bq0[kh], accI[1], 0, 0, 0);
            }
            if (kc + 2 < 20) {           // refill slot 0 with kc+2 (2-deep)
#pragma unroll
                for (int kh = 0; kh < 2; kh++)
                    bq0[kh] = *(const uint4*)(xb + (size_t)(kc + 2) * 65536 + kh * 32);
#pragma unroll
                for (int mi2 = 0; mi2 < 2; mi2++)
#pragma unroll
                    for (int kh = 0; kh < 2; kh++)
                        avA[mi2][kh] = ((const uint4*)wIt)[(kc + 2) * 256 + (mi2 << 7) + (kh << 6) + l];
            }
            // MFMA kc+1
#pragma unroll
            for (int kh = 0; kh < 2; kh++) {
                accI[0] = __builtin_amdgcn_mfma_f32_32x32x16_bf16(*(short8*)&avB[0][kh], *(short8*)&bq1[kh], accI[0], 0, 0, 0);
                accI[1] = __builtin_amdgcn_mfma_f32_32x32x16_bf16(*(short8*)&avB[1][kh], *(short8*)&bq1[kh], accI[1], 0, 0, 0);
            }
            if (kc + 3 < 20) {           // refill slot 1 with kc+3
#pragma unroll
                for (int kh = 0; kh < 2; kh++)
                    bq1[kh] = *(const uint4*)(xb + (size_t)(kc + 3) * 65536 + kh * 32);
            }
        }
        // bias + relu (in place), pixel L2-norm across 64 oc
        float ss = 0.f;
#pragma unroll
        for (int mi2 = 0; mi2 < 2; mi2++)
#pragma unroll
            for (int rg = 0; rg < 4; rg++) {
                float4 bb = *(const float4*)&biasI[mi2 * 32 + 8 * rg + 4 * (l >> 5)];
#pragma unroll
                for (int q = 0; q < 4; q++) {
                    float bv = (q == 0) ? bb.x : (q == 1) ? bb.y : (q == 2) ? bb.z : bb.w;
                    float t = fmaxf(accI[mi2][rg * 4 + q] + bv, 0.f);
                    accI[mi2][rg * 4 + q] = t;
                    ss = fmaf(t, t, ss);
                }
            }
        ss += __shfl_xor(ss, 32);        // lanes l and l+32 hold the same px
        float inv = 1.f / fmaxf(sqrtf(ss), 1e-12f);
        if (spx < 216) {
#pragma unroll
            for (int mi2 = 0; mi2 < 2; mi2++)
#pragma unroll
                for (int rg = 0; rg < 4; rg++) {
                    unsigned d0 = pack_bf16(accI[mi2][rg * 4 + 0] * inv, accI[mi2][rg * 4 + 1] * inv);
                    unsigned d1 = pack_bf16(accI[mi2][rg * 4 + 2] * inv, accI[mi2][rg * 4 + 3] * inv);
                    if (!valid) { d0 = 0u; d1 = 0u; }
                    *(uint2*)&slab[spx * 72 + mi2 * 32 + 8 * rg + 4 * (l >> 5)] = make_uint2(d0, d1);
                }
        }
    }
    __syncthreads();

    // ---- phase 0b: invD (featureL2Norm of corr) ----
    if (tid < 512) {
        int px = tid >> 3, part = tid & 7;
        int rh = px >> 5, rw = px & 31;
        float ctr[8];
        const unsigned* cp = (const unsigned*)&slab[((rh + 2) * 36 + rw + 2) * 72 + part * 8];
#pragma unroll
        for (int d = 0; d < 4; d++) { ctr[2 * d] = bflo(cp[d]); ctr[2 * d + 1] = bfhi(cp[d]); }
        float sum = 0.f;
#pragma unroll
        for (int k = 0; k < 25; k++) {
            const int kh = k / 5, kw = k % 5;
            const unsigned* nb = (const unsigned*)&slab[((rh + kh) * 36 + rw + kw) * 72 + part * 8];
#pragma unroll
            for (int d = 0; d < 4; d++) {
                float q0 = bflo(nb[d]) * ctr[2 * d];
                float q1 = bfhi(nb[d]) * ctr[2 * d + 1];
                sum = fmaf(q0, q0, sum); sum = fmaf(q1, q1, sum);
            }
        }
        sum += __shfl_xor(sum, 1);
        sum += __shfl_xor(sum, 2);
        sum += __shfl_xor(sum, 4);
        if (part == 0) invDs[px] = rsqrtf(sum + 1e-6f);
    }
    __syncthreads();

    // ---- phase 0c: normalized centers ----
    if (tid < 512) {
        int px = tid >> 3, q = tid & 7;
        int spx = ((px >> 5) + 2) * 36 + (px & 31) + 2;
        const unsigned* src = (const unsigned*)&slab[spx * 72 + q * 8];
        float iv = invDs[px];
        unsigned d[4];
#pragma unroll
        for (int dd = 0; dd < 4; dd++)
            d[dd] = pk_hu(bflo(src[dd]) * iv, bfhi(src[dd]) * iv);
        *(uint4*)&ctrs[px * 72 + q * 8] = make_uint4(d[0], d[1], d[2], d[3]);
    }
    __syncthreads();

    // ---- phase 1: emb GEMM, 8-kc chunks, rolling A/B prefetch ----
    const uint4* A = (const uint4*)wEt + (size_t)(mt * 52) * 512;

    f32x16 acc[2][2];
#pragma unroll
    for (int i = 0; i < 2; i++)
#pragma unroll
        for (int j = 0; j < 2; j++)
#pragma unroll
            for (int r = 0; r < 16; r++) acc[i][j][r] = 0.f;

    uint4 avc[2][2];
#pragma unroll
    for (int mi = 0; mi < 2; mi++)
#pragma unroll
        for (int kh = 0; kh < 2; kh++)
            avc[mi][kh] = A[(((mf0 + mi) * 2 + kh) << 6) + l];

    // gen chunk 0 (kc 0..7)
#pragma unroll
    for (int k = 0; k < 4; k++) {
        int u = tid + k * 640;
        if (u < 2048) {
            uint4 f = gen_feat_unit(slab, ctrs, (u >> 8), u & 255);
            *(uint4*)&stg[u * 16] = f;
        }
    }
    __syncthreads();

    uint4 bvc[2][2];
#pragma unroll
    for (int ni = 0; ni < 2; ni++)
#pragma unroll
        for (int kh = 0; kh < 2; kh++)
            bvc[ni][kh] = *(const uint4*)&stg[((ni << 7) + (kh << 6) + l) * 16];

#pragma unroll 1
    for (int c = 0; c < 6; c++) {
        const int cur = c & 1, nxt = cur ^ 1;
        const int base = c * 8;
        // generate next chunk into the free buffer (chunk c+1: 8 kc, last is 4)
        {
            const int nunits = (c < 5) ? 2048 : 1024;
            const int nbase = base + 8;
#pragma unroll
            for (int k = 0; k < 4; k++) {
                int u = tid + k * 640;
                if (u < nunits) {
                    uint4 f = gen_feat_unit(slab, ctrs, nbase + (u >> 8), u & 255);
                    *(uint4*)&stg[nxt * 32768 + u * 16] = f;
                }
            }
        }
#pragma unroll
        for (int kcL = 0; kcL < 8; kcL++) {
            const int kc = base + kcL;
            uint4 avn[2][2];
#pragma unroll
            for (int mi = 0; mi < 2; mi++)
#pragma unroll
                for (int kh = 0; kh < 2; kh++)
                    avn[mi][kh] = A[(size_t)(kc + 1) * 512 + (((mf0 + mi) * 2 + kh) << 6) + l];
            uint4 bvn[2][2];
            if (kcL < 7) {
#pragma unroll
                for (int ni = 0; ni < 2; ni++)
#pragma unroll
                    for (int kh = 0; kh < 2; kh++)
                        bvn[ni][kh] = *(const uint4*)&stg[cur * 32768 + ((kcL + 1) * 256 + (ni << 7) + (kh << 6) + l) * 16];
            }
#pragma unroll
            for (int kh = 0; kh < 2; kh++) {
                acc[0][0] = __builtin_amdgcn_mfma_f32_32x32x16_bf16(*(short8*)&avc[0][kh], *(short8*)&bvc[0][kh], acc[0][0], 0, 0, 0);
                acc[0][1] = __builtin_amdgcn_mfma_f32_32x32x16_bf16(*(short8*)&avc[0][kh], *(short8*)&bvc[1][kh], acc[0][1], 0, 0, 0);
                acc[1][0] = __builtin_amdgcn_mfma_f32_32x32x16_bf16(*(short8*)&avc[1][kh], *(short8*)&bvc[0][kh], acc[1][0], 0, 0, 0);
                acc[1][1] = __builtin_amdgcn_mfma_f32_32x32x16_bf16(*(short8*)&avc[1][kh], *(short8*)&bvc[1][kh], acc[1][1], 0, 0, 0);
            }
#pragma unroll
            for (int mi = 0; mi < 2; mi++)
#pragma unroll
                for (int kh = 0; kh < 2; kh++) avc[mi][kh] = avn[mi][kh];
            if (kcL < 7) {
#pragma unroll
                for (int ni = 0; ni < 2; ni++)
#pragma unroll
                    for (int kh = 0; kh < 2; kh++) bvc[ni][kh] = bvn[ni][kh];
            }
        }
        __syncthreads();
        // load first bv of next chunk from the buffer just generated
#pragma unroll
        for (int ni = 0; ni < 2; ni++)
#pragma unroll
            for (int kh = 0; kh < 2; kh++)
                bvc[ni][kh] = *(const uint4*)&stg[nxt * 32768 + ((ni << 7) + (kh << 6) + l) * 16];
    }
    // final chunk: kc 48..51, buffer index 6&1 = 0
#pragma unroll
    for (int kcL = 0; kcL < 4; kcL++) {
        const int kc = 48 + kcL;
        uint4 avn[2][2], bvn[2][2];
        if (kcL < 3) {
#pragma unroll
            for (int mi = 0; mi < 2; mi++)
#pragma unroll
                for (int kh = 0; kh < 2; kh++)
                    avn[mi][kh] = A[(size_t)(kc + 1) * 512 + (((mf0 + mi) * 2 + kh) << 6) + l];
#pragma unroll
            for (int ni = 0; ni < 2; ni++)
#pragma unroll
                for (int kh = 0; kh < 2; kh++)
                    bvn[ni][kh] = *(const uint4*)&stg[((kcL + 1) * 256 + (ni << 7) + (kh << 6) + l) * 16];
        }
#pragma unroll
        for (int kh = 0; kh < 2; kh++) {
            acc[0][0] = __builtin_amdgcn_mfma_f32_32x32x16_bf16(*(short8*)&avc[0][kh], *(short8*)&bvc[0][kh], acc[0][0], 0, 0, 0);
            acc[0][1] = __builtin_amdgcn_mfma_f32_32x32x16_bf16(*(short8*)&avc[0][kh], *(short8*)&bvc[1][kh], acc[0][1], 0, 0, 0);
            acc[1][0] = __builtin_amdgcn_mfma_f32_32x32x16_bf16(*(short8*)&avc[1][kh], *(short8*)&bvc[0][kh], acc[1][0], 0, 0, 0);
            acc[1][1] = __builtin_amdgcn_mfma_f32_32x32x16_bf16(*(short8*)&avc[1][kh], *(short8*)&bvc[1][kh], acc[1][1], 0, 0, 0);
        }
        if (kcL < 3) {
#pragma unroll
            for (int mi = 0; mi < 2; mi++)
#pragma unroll
                for (int kh = 0; kh < 2; kh++) avc[mi][kh] = avn[mi][kh];
#pragma unroll
            for (int ni = 0; ni < 2; ni++)
#pragma unroll
                for (int kh = 0; kh < 2; kh++) bvc[ni][kh] = bvn[ni][kh];
        }
    }
    __syncthreads();                     // all phase-1 LDS reads done: Ep may alias

    // ---- phase 2: bias+relu epilogue into Ep (out-GEMM B-frag order) ----
#pragma unroll
    for (int mi = 0; mi < 2; mi++) {
        const int kbase = (w * 2 + mi) * 256;
#pragma unroll
        for (int ni = 0; ni < 2; ni++) {
#pragma unroll
            for (int rg = 0; rg < 4; rg++) {
                int ocb = w * 64 + mi * 32 + 8 * rg + 4 * (l >> 5);
                float4 bb = *(const float4*)&biasE[ocb];
                unsigned d0 = pack_bf16(fmaxf(acc[mi][ni][rg * 4 + 0] + bb.x, 0.f),
                                        fmaxf(acc[mi][ni][rg * 4 + 1] + bb.y, 0.f));
                unsigned d1 = pack_bf16(fmaxf(acc[mi][ni][rg * 4 + 2] + bb.z, 0.f),
                                        fmaxf(acc[mi][ni][rg * 4 + 3] + bb.w, 0.f));
                int unit = kbase + (ni << 7) + ((rg >> 1) << 6) + ((rg & 1) << 5) + (l & 31);
                ((uint2*)Ep)[unit * 2 + (l >> 5)] = make_uint2(d0, d1);
            }
        }
    }
    __syncthreads();

    // ---- phase 3: out GEMM. B = Ep (LDS), A = wOt (L2), rolling prefetch ----
    const int p0 = pt * 64;
    const int hw0 = p0 & 1023;
    const uint4* Ao = (const uint4*)wOt + (size_t)(mt * 20) * 512;

    f32x16 acc2[2][2];
#pragma unroll
    for (int i = 0; i < 2; i++)
#pragma unroll
        for (int j = 0; j < 2; j++)
#pragma unroll
            for (int r = 0; r < 16; r++) acc2[i][j][r] = 0.f;

    uint4 aoc[2][2], boc[2][2];
#pragma unroll
    for (int mi = 0; mi < 2; mi++)
#pragma unroll
        for (int kh = 0; kh < 2; kh++)
            aoc[mi][kh] = Ao[(((mf0 + mi) * 2 + kh) << 6) + l];
#pragma unroll
    for (int ni = 0; ni < 2; ni++)
#pragma unroll
        for (int kh = 0; kh < 2; kh++)
            boc[ni][kh] = Ep[(ni << 7) + (kh << 6) + l];

#pragma unroll 4
    for (int kc = 0; kc < 20; kc++) {
        uint4 aon[2][2], bon[2][2];
        if (kc < 19) {
#pragma unroll
            for (int mi = 0; mi < 2; mi++)
#pragma unroll
                for (int kh = 0; kh < 2; kh++)
                    aon[mi][kh] = Ao[(size_t)(kc + 1) * 512 + (((mf0 + mi) * 2 + kh) << 6) + l];
#pragma unroll
            for (int ni = 0; ni < 2; ni++)
#pragma unroll
                for (int kh = 0; kh < 2; kh++)
                    bon[ni][kh] = Ep[(kc + 1) * 256 + (ni << 7) + (kh << 6) + l];
        }
#pragma unroll
        for (int kh = 0; kh < 2; kh++) {
            acc2[0][0] = __builtin_amdgcn_mfma_f32_32x32x16_bf16(*(short8*)&aoc[0][kh], *(short8*)&boc[0][kh], acc2[0][0], 0, 0, 0);
            acc2[0][1] = __builtin_amdgcn_mfma_f32_32x32x16_bf16(*(short8*)&aoc[0][kh], *(short8*)&boc[1][kh], acc2[0][1], 0, 0, 0);
            acc2[1][0] = __builtin_amdgcn_mfma_f32_32x32x16_bf16(*(short8*)&aoc[1][kh], *(short8*)&boc[0][kh], acc2[1][0], 0, 0, 0);
            acc2[1][1] = __builtin_amdgcn_mfma_f32_32x32x16_bf16(*(short8*)&aoc[1][kh], *(short8*)&boc[1][kh], acc2[1][1], 0, 0, 0);
        }
        if (kc < 19) {
#pragma unroll
            for (int mi = 0; mi < 2; mi++)
#pragma unroll
                for (int kh = 0; kh < 2; kh++) aoc[mi][kh] = aon[mi][kh];
#pragma unroll
            for (int ni = 0; ni < 2; ni++)
#pragma unroll
                for (int kh = 0; kh < 2; kh++) boc[ni][kh] = bon[ni][kh];
        }
    }

#pragma unroll
    for (int mi = 0; mi < 2; mi++)
#pragma unroll
        for (int ni = 0; ni < 2; ni++) {
            int pxl = ni * 32 + (l & 31);
#pragma unroll
            for (int r = 0; r < 16; r++) {
                int oc = w * 64 + mi * 32 + (r & 3) + 8 * (r >> 2) + 4 * (l >> 5);
                out[((size_t)b * 640 + oc) * 1024 + hw0 + pxl] = acc2[mi][ni][r] + biasO[oc];
            }
        }
}

// ===========================================================================
extern "C" void kernel_launch(void* const* d_in, const int* in_sizes, int n_in,
                              void* d_out, int out_size, void* d_ws, size_t ws_size,
                              hipStream_t stream)
{
    const float* x    = (const float*)d_in[0];
    const float* g1   = (const float*)d_in[1];
    const float* b1   = (const float*)d_in[2];
    const float* m1   = (const float*)d_in[3];
    const float* v1   = (const float*)d_in[4];
    const float* w_in = (const float*)d_in[5];
    const float* gi   = (const float*)d_in[6];
    const float* bi   = (const float*)d_in[7];
    const float* mi   = (const float*)d_in[8];
    const float* vi   = (const float*)d_in[9];
    const float* w_emb= (const float*)d_in[10];
    const float* ge   = (const float*)d_in[11];
    const float* be   = (const float*)d_in[12];
    const float* me   = (const float*)d_in[13];
    const float* ve   = (const float*)d_in[14];
    const float* w_out= (const float*)d_in[15];
    const float* go   = (const float*)d_in[16];
    const float* bo   = (const float*)d_in[17];
    const float* mo   = (const float*)d_in[18];
    const float* vo   = (const float*)d_in[19];

    char* ws = (char*)d_ws;
    float*    biasI = (float*)(ws + 5120);
    float*    biasE = (float*)(ws + 5376);
    float*    biasO = (float*)(ws + 7936);
    unsigned* wIt   = (unsigned*)(ws + 16384);
    unsigned* wOt   = (unsigned*)(ws + 98304);
    unsigned* wEt   = (unsigned*)(ws + 917504);    // ends 3,047,424
    unsigned* xpk   = (unsigned*)(ws + 3047424);   // 20,971,520 B -> ends 24,018,944
    float*    out   = (float*)d_out;

    k_prepAll<<<1592, 256, 0, stream>>>(x, g1, b1, m1, v1, w_in, gi, bi, mi, vi,
                                        w_emb, ge, be, me, ve, w_out, go, bo, mo, vo,
                                        biasI, biasE, biasO, wIt, wEt, wOt, xpk);
    k_mega<<<256, 640, 0, stream>>>(xpk, wIt, biasI,
                                    wEt, biasE, wOt, biasO, out);
}